// Round 1
// baseline (35657.300 us; speedup 1.0000x reference)
//
#include <hip/hip_runtime.h>
#include <stdint.h>

#define HD   1024   // hidden size
#define FH   4096   // 4*HD
#define TT   256    // time steps
#define BAT  1024   // batch

typedef __bf16 bf16_t;
typedef __bf16 bf16x8 __attribute__((ext_vector_type(8)));
typedef float  f32x4  __attribute__((ext_vector_type(4)));

__device__ __forceinline__ float sigm(float x)     { return 1.0f/(1.0f + __expf(-x)); }
__device__ __forceinline__ float tanhfast(float x) { return 1.0f - 2.0f/(__expf(2.0f*x) + 1.0f); }

// Gate-column permutation:
//   p = nt*256 + sub*64 + g*16 + low   (nt in [0,16), sub in [0,4), g in [0,4), low in [0,16))
//   hidden unit = nt*64 + sub*16 + low ; original W row = g*1024 + unit
// => block (mt,nt), wave-col cb==sub, acc-frag index == gate g, lane&15 == low:
//    all 4 gates of a unit live in the same lane.  Cell update is lane-local.
__global__ void prep_weights(const float* __restrict__ Whh0, const float* __restrict__ Wih1,
                             const float* __restrict__ Whh1, const float* __restrict__ bih0,
                             const float* __restrict__ bhh0, const float* __restrict__ bih1,
                             const float* __restrict__ bhh1, const float* __restrict__ Wih0,
                             bf16_t* __restrict__ W0p, bf16_t* __restrict__ W1ip, bf16_t* __restrict__ W1hp,
                             float* __restrict__ bias0p, float* __restrict__ bias1p, float* __restrict__ wih0p)
{
    int p   = blockIdx.x;             // 0..4095 permuted gate-row index
    int nt  = p >> 8;
    int c   = p & 255;
    int sub = c >> 6;
    int g   = (c >> 4) & 3;
    int low = c & 15;
    int unit = nt*64 + sub*16 + low;
    int orig = g*HD + unit;

    const float* s0 = Whh0 + (size_t)orig*HD;
    const float* s1 = Wih1 + (size_t)orig*HD;
    const float* s2 = Whh1 + (size_t)orig*HD;
    bf16_t* d0 = W0p  + (size_t)p*HD;
    bf16_t* d1 = W1ip + (size_t)p*HD;
    bf16_t* d2 = W1hp + (size_t)p*HD;
    for (int k = threadIdx.x; k < HD; k += blockDim.x) {
        d0[k] = (bf16_t)s0[k];
        d1[k] = (bf16_t)s1[k];
        d2[k] = (bf16_t)s2[k];
    }
    if (threadIdx.x == 0) {
        bias0p[p] = bih0[orig] + bhh0[orig];
        bias1p[p] = bih1[orig] + bhh1[orig];
        wih0p[p]  = Wih0[orig];
    }
}

__global__ void init_states(const float* __restrict__ h0, const float* __restrict__ c0in,
                            bf16_t* __restrict__ ha0, bf16_t* __restrict__ hb0,
                            float* __restrict__ cl0, float* __restrict__ cl1)
{
    int i = blockIdx.x * blockDim.x + threadIdx.x;   // 0 .. 1048575
    ha0[i] = (bf16_t)h0[i];
    hb0[i] = (bf16_t)h0[1048576 + i];
    cl0[i] = c0in[i];
    cl1[i] = c0in[1048576 + i];
}

// ---------------- layer 0: gates = x*wih0 + ha_prev @ W0p^T + bias ; cell -> ha_new, c0 ----------------
__global__ __launch_bounds__(512) void step_l0(
    const bf16_t* __restrict__ W0p, const float* __restrict__ bias0p, const float* __restrict__ wih0p,
    const bf16_t* __restrict__ ha_in, bf16_t* __restrict__ ha_out,
    float* __restrict__ cl0, const float* __restrict__ preds, int t)
{
    int bidx = blockIdx.x;
    int nt = (bidx & 7) | (((bidx >> 3) & 1) << 3);   // XCD-local N-tile pairing
    int mt = bidx >> 4;
    int tid  = threadIdx.x;
    int lane = tid & 63, w = tid >> 6;
    int rb = w >> 2, cb = w & 3;
    int l15 = lane & 15, lg = lane >> 4;

    int rowbase = mt*64 + rb*32;
    const bf16_t* Abase = ha_in + (size_t)(rowbase + l15)*HD + 8*lg;
    const bf16_t* Bbase = W0p   + (size_t)(nt*256 + cb*64 + l15)*HD + 8*lg;

    f32x4 acc[2][4];
    #pragma unroll
    for (int mi = 0; mi < 2; ++mi)
        #pragma unroll
        for (int g = 0; g < 4; ++g) acc[mi][g] = f32x4{0.f, 0.f, 0.f, 0.f};

    #pragma unroll 4
    for (int k0 = 0; k0 < HD; k0 += 32) {
        bf16x8 a0 = *reinterpret_cast<const bf16x8*>(Abase + k0);
        bf16x8 a1 = *reinterpret_cast<const bf16x8*>(Abase + 16*HD + k0);
        bf16x8 b0 = *reinterpret_cast<const bf16x8*>(Bbase + k0);
        bf16x8 b1 = *reinterpret_cast<const bf16x8*>(Bbase + 16*HD + k0);
        bf16x8 b2 = *reinterpret_cast<const bf16x8*>(Bbase + 32*HD + k0);
        bf16x8 b3 = *reinterpret_cast<const bf16x8*>(Bbase + 48*HD + k0);
        acc[0][0] = __builtin_amdgcn_mfma_f32_16x16x32_bf16(a0, b0, acc[0][0], 0, 0, 0);
        acc[0][1] = __builtin_amdgcn_mfma_f32_16x16x32_bf16(a0, b1, acc[0][1], 0, 0, 0);
        acc[0][2] = __builtin_amdgcn_mfma_f32_16x16x32_bf16(a0, b2, acc[0][2], 0, 0, 0);
        acc[0][3] = __builtin_amdgcn_mfma_f32_16x16x32_bf16(a0, b3, acc[0][3], 0, 0, 0);
        acc[1][0] = __builtin_amdgcn_mfma_f32_16x16x32_bf16(a1, b0, acc[1][0], 0, 0, 0);
        acc[1][1] = __builtin_amdgcn_mfma_f32_16x16x32_bf16(a1, b1, acc[1][1], 0, 0, 0);
        acc[1][2] = __builtin_amdgcn_mfma_f32_16x16x32_bf16(a1, b2, acc[1][2], 0, 0, 0);
        acc[1][3] = __builtin_amdgcn_mfma_f32_16x16x32_bf16(a1, b3, acc[1][3], 0, 0, 0);
    }

    int pbase = nt*256 + cb*64 + l15;
    float bi[4], wv[4];
    #pragma unroll
    for (int g = 0; g < 4; ++g) { bi[g] = bias0p[pbase + g*16]; wv[g] = wih0p[pbase + g*16]; }
    int j = nt*64 + cb*16 + l15;   // hidden unit owned by this lane

    #pragma unroll
    for (int mi = 0; mi < 2; ++mi) {
        #pragma unroll
        for (int r = 0; r < 4; ++r) {
            int row = rowbase + mi*16 + lg*4 + r;           // D row = 4*(lane>>4)+reg (m89)
            float x = (t > 0) ? preds[(size_t)row*TT + (t-1)] : 0.f;
            float gi = acc[mi][0][r] + bi[0] + x*wv[0];
            float gf = acc[mi][1][r] + bi[1] + x*wv[1];
            float gg = acc[mi][2][r] + bi[2] + x*wv[2];
            float go = acc[mi][3][r] + bi[3] + x*wv[3];
            size_t off = (size_t)row*HD + j;
            float cold = cl0[off];
            float cn = sigm(gf)*cold + sigm(gi)*tanhfast(gg);
            cl0[off] = cn;
            ha_out[off] = (bf16_t)(sigm(go)*tanhfast(cn));
        }
    }
}

// ------- layer 1: gates = ha_new @ W1ip^T + hb_prev @ W1hp^T + bias ; cell -> hb_new, c1 ; pred -------
__global__ __launch_bounds__(512) void step_l1(
    const bf16_t* __restrict__ W1ip, const bf16_t* __restrict__ W1hp, const float* __restrict__ bias1p,
    const bf16_t* __restrict__ ha_new, const bf16_t* __restrict__ hb_in, bf16_t* __restrict__ hb_out,
    float* __restrict__ cl1, const float* __restrict__ Wout, const float* __restrict__ bout,
    float* __restrict__ preds, int t)
{
    int bidx = blockIdx.x;
    int nt = (bidx & 7) | (((bidx >> 3) & 1) << 3);
    int mt = bidx >> 4;
    int tid  = threadIdx.x;
    int lane = tid & 63, w = tid >> 6;
    int rb = w >> 2, cb = w & 3;
    int l15 = lane & 15, lg = lane >> 4;

    int rowbase = mt*64 + rb*32;
    const bf16_t* A1 = ha_new + (size_t)(rowbase + l15)*HD + 8*lg;
    const bf16_t* A2 = hb_in  + (size_t)(rowbase + l15)*HD + 8*lg;
    const bf16_t* B1 = W1ip   + (size_t)(nt*256 + cb*64 + l15)*HD + 8*lg;
    const bf16_t* B2 = W1hp   + (size_t)(nt*256 + cb*64 + l15)*HD + 8*lg;

    f32x4 acc[2][4];
    #pragma unroll
    for (int mi = 0; mi < 2; ++mi)
        #pragma unroll
        for (int g = 0; g < 4; ++g) acc[mi][g] = f32x4{0.f, 0.f, 0.f, 0.f};

    #pragma unroll 2
    for (int k0 = 0; k0 < HD; k0 += 32) {
        bf16x8 a10 = *reinterpret_cast<const bf16x8*>(A1 + k0);
        bf16x8 a11 = *reinterpret_cast<const bf16x8*>(A1 + 16*HD + k0);
        bf16x8 a20 = *reinterpret_cast<const bf16x8*>(A2 + k0);
        bf16x8 a21 = *reinterpret_cast<const bf16x8*>(A2 + 16*HD + k0);
        bf16x8 b10 = *reinterpret_cast<const bf16x8*>(B1 + k0);
        bf16x8 b11 = *reinterpret_cast<const bf16x8*>(B1 + 16*HD + k0);
        bf16x8 b12 = *reinterpret_cast<const bf16x8*>(B1 + 32*HD + k0);
        bf16x8 b13 = *reinterpret_cast<const bf16x8*>(B1 + 48*HD + k0);
        bf16x8 b20 = *reinterpret_cast<const bf16x8*>(B2 + k0);
        bf16x8 b21 = *reinterpret_cast<const bf16x8*>(B2 + 16*HD + k0);
        bf16x8 b22 = *reinterpret_cast<const bf16x8*>(B2 + 32*HD + k0);
        bf16x8 b23 = *reinterpret_cast<const bf16x8*>(B2 + 48*HD + k0);
        acc[0][0] = __builtin_amdgcn_mfma_f32_16x16x32_bf16(a10, b10, acc[0][0], 0, 0, 0);
        acc[0][1] = __builtin_amdgcn_mfma_f32_16x16x32_bf16(a10, b11, acc[0][1], 0, 0, 0);
        acc[0][2] = __builtin_amdgcn_mfma_f32_16x16x32_bf16(a10, b12, acc[0][2], 0, 0, 0);
        acc[0][3] = __builtin_amdgcn_mfma_f32_16x16x32_bf16(a10, b13, acc[0][3], 0, 0, 0);
        acc[1][0] = __builtin_amdgcn_mfma_f32_16x16x32_bf16(a11, b10, acc[1][0], 0, 0, 0);
        acc[1][1] = __builtin_amdgcn_mfma_f32_16x16x32_bf16(a11, b11, acc[1][1], 0, 0, 0);
        acc[1][2] = __builtin_amdgcn_mfma_f32_16x16x32_bf16(a11, b12, acc[1][2], 0, 0, 0);
        acc[1][3] = __builtin_amdgcn_mfma_f32_16x16x32_bf16(a11, b13, acc[1][3], 0, 0, 0);
        acc[0][0] = __builtin_amdgcn_mfma_f32_16x16x32_bf16(a20, b20, acc[0][0], 0, 0, 0);
        acc[0][1] = __builtin_amdgcn_mfma_f32_16x16x32_bf16(a20, b21, acc[0][1], 0, 0, 0);
        acc[0][2] = __builtin_amdgcn_mfma_f32_16x16x32_bf16(a20, b22, acc[0][2], 0, 0, 0);
        acc[0][3] = __builtin_amdgcn_mfma_f32_16x16x32_bf16(a20, b23, acc[0][3], 0, 0, 0);
        acc[1][0] = __builtin_amdgcn_mfma_f32_16x16x32_bf16(a21, b20, acc[1][0], 0, 0, 0);
        acc[1][1] = __builtin_amdgcn_mfma_f32_16x16x32_bf16(a21, b21, acc[1][1], 0, 0, 0);
        acc[1][2] = __builtin_amdgcn_mfma_f32_16x16x32_bf16(a21, b22, acc[1][2], 0, 0, 0);
        acc[1][3] = __builtin_amdgcn_mfma_f32_16x16x32_bf16(a21, b23, acc[1][3], 0, 0, 0);
    }

    int pbase = nt*256 + cb*64 + l15;
    float bi[4];
    #pragma unroll
    for (int g = 0; g < 4; ++g) bi[g] = bias1p[pbase + g*16];
    int j = nt*64 + cb*16 + l15;
    float wout = Wout[j];

    float hn[2][4];
    #pragma unroll
    for (int mi = 0; mi < 2; ++mi) {
        #pragma unroll
        for (int r = 0; r < 4; ++r) {
            int row = rowbase + mi*16 + lg*4 + r;
            float gi = acc[mi][0][r] + bi[0];
            float gf = acc[mi][1][r] + bi[1];
            float gg = acc[mi][2][r] + bi[2];
            float go = acc[mi][3][r] + bi[3];
            size_t off = (size_t)row*HD + j;
            float cold = cl1[off];
            float cn = sigm(gf)*cold + sigm(gi)*tanhfast(gg);
            cl1[off] = cn;
            float h = sigm(go)*tanhfast(cn);
            hn[mi][r] = h;
            hb_out[off] = (bf16_t)h;
        }
    }

    // output projection: pred[row] += sum_j h[row][j]*Wout[j]  (reduce 16 lanes -> 1)
    #pragma unroll
    for (int mi = 0; mi < 2; ++mi) {
        #pragma unroll
        for (int r = 0; r < 4; ++r) {
            float v = hn[mi][r] * wout;
            v += __shfl_xor(v, 1, 64);
            v += __shfl_xor(v, 2, 64);
            v += __shfl_xor(v, 4, 64);
            v += __shfl_xor(v, 8, 64);
            if (l15 == 0) {
                int row = rowbase + mi*16 + lg*4 + r;
                if (nt == 0 && cb == 0) v += bout[0];
                atomicAdd(&preds[(size_t)row*TT + t], v);
            }
        }
    }
}

__global__ void loss_kernel(const float* __restrict__ preds, const float* __restrict__ targets,
                            float* __restrict__ lossp)
{
    int i = blockIdx.x * blockDim.x + threadIdx.x;   // 0 .. 262143
    float d = preds[i] - targets[i];
    float v = d*d;
    v += __shfl_xor(v, 1, 64);
    v += __shfl_xor(v, 2, 64);
    v += __shfl_xor(v, 4, 64);
    v += __shfl_xor(v, 8, 64);
    v += __shfl_xor(v, 16, 64);
    v += __shfl_xor(v, 32, 64);
    if ((threadIdx.x & 63) == 0) atomicAdd(lossp, v * (1.0f/1024.0f));
}

extern "C" void kernel_launch(void* const* d_in, const int* in_sizes, int n_in,
                              void* d_out, int out_size, void* d_ws, size_t ws_size,
                              hipStream_t stream)
{
    const float* outputs = (const float*)d_in[0];
    const float* h0      = (const float*)d_in[1];
    const float* c0      = (const float*)d_in[2];
    const float* Wih0    = (const float*)d_in[3];
    const float* Whh0    = (const float*)d_in[4];
    const float* bih0    = (const float*)d_in[5];
    const float* bhh0    = (const float*)d_in[6];
    const float* Wih1    = (const float*)d_in[7];
    const float* Whh1    = (const float*)d_in[8];
    const float* bih1    = (const float*)d_in[9];
    const float* bhh1    = (const float*)d_in[10];
    const float* Wout    = (const float*)d_in[11];
    const float* bout    = (const float*)d_in[12];

    uint8_t* ws = (uint8_t*)d_ws;
    size_t o = 0;
    auto alloc = [&](size_t bytes) { void* p = ws + o; o += (bytes + 255) & ~(size_t)255; return p; };
    bf16_t* W0p    = (bf16_t*)alloc((size_t)FH*HD*2);
    bf16_t* W1ip   = (bf16_t*)alloc((size_t)FH*HD*2);
    bf16_t* W1hp   = (bf16_t*)alloc((size_t)FH*HD*2);
    bf16_t* haB[2] = { (bf16_t*)alloc((size_t)BAT*HD*2), (bf16_t*)alloc((size_t)BAT*HD*2) };
    bf16_t* hbB[2] = { (bf16_t*)alloc((size_t)BAT*HD*2), (bf16_t*)alloc((size_t)BAT*HD*2) };
    float*  cl0    = (float*)alloc((size_t)BAT*HD*4);
    float*  cl1    = (float*)alloc((size_t)BAT*HD*4);
    float*  bias0p = (float*)alloc(FH*4);
    float*  bias1p = (float*)alloc(FH*4);
    float*  wih0p  = (float*)alloc(FH*4);

    float* preds = (float*)d_out;                       // [BAT][TT] then loss scalar
    hipMemsetAsync(d_out, 0, (size_t)out_size*4, stream);

    prep_weights<<<FH, 256, 0, stream>>>(Whh0, Wih1, Whh1, bih0, bhh0, bih1, bhh1, Wih0,
                                         W0p, W1ip, W1hp, bias0p, bias1p, wih0p);
    init_states<<<4096, 256, 0, stream>>>(h0, c0, haB[0], hbB[0], cl0, cl1);

    for (int t = 0; t < TT; ++t) {
        bf16_t* haA   = haB[t & 1];
        bf16_t* haNew = haB[(t + 1) & 1];
        bf16_t* hbA   = hbB[t & 1];
        bf16_t* hbNew = hbB[(t + 1) & 1];
        step_l0<<<256, 512, 0, stream>>>(W0p, bias0p, wih0p, haA, haNew, cl0, preds, t);
        step_l1<<<256, 512, 0, stream>>>(W1ip, W1hp, bias1p, haNew, hbA, hbNew, cl1,
                                         Wout, bout, preds, t);
    }
    loss_kernel<<<1024, 256, 0, stream>>>(preds, outputs, preds + (size_t)BAT*TT);
}

// Round 4
// 11598.602 us; speedup vs baseline: 3.0743x; 3.0743x over previous
//
#include <hip/hip_runtime.h>
#include <stdint.h>

#define HD   1024
#define FH   4096
#define TT   256
#define BAT  1024
#define BM   128
#define BN   128   // gate-cols per block
#define BK   64

typedef __bf16 bf16_t;
typedef __bf16 bf16x8 __attribute__((ext_vector_type(8)));
typedef float  f32x4  __attribute__((ext_vector_type(4)));

__device__ __forceinline__ float sigm(float x)     { return 1.0f/(1.0f + __expf(-x)); }
__device__ __forceinline__ float tanhfast(float x) { return 1.0f - 2.0f/(__expf(2.0f*x) + 1.0f); }

__device__ __forceinline__ void gload_lds16(const void* g, void* l) {
    __builtin_amdgcn_global_load_lds((const __attribute__((address_space(1))) void*)g,
                                     (__attribute__((address_space(3))) void*)l, 16, 0, 0);
}

// Permutation: p = nt*128 + cb*64 + g*16 + low  (nt<32, cb<2, g<4, low<16)
//   unit = nt*32 + cb*16 + low ; orig W row = g*1024 + unit
// Storage swizzle (T2, rule #21): element u of row r stored at u ^ ((r&7)<<3).
__global__ void prep_weights(const float* __restrict__ Whh0, const float* __restrict__ Wih1,
                             const float* __restrict__ Whh1, const float* __restrict__ bih0,
                             const float* __restrict__ bhh0, const float* __restrict__ bih1,
                             const float* __restrict__ bhh1, const float* __restrict__ Wih0,
                             bf16_t* __restrict__ W0p, bf16_t* __restrict__ W1cat,
                             float* __restrict__ bias0p, float* __restrict__ bias1p,
                             float* __restrict__ wih0p)
{
    int p   = blockIdx.x;            // 0..4095
    int nt  = p >> 7;
    int c   = p & 127;
    int cb  = c >> 6;
    int g   = (c >> 4) & 3;
    int low = c & 15;
    int unit = nt*32 + cb*16 + low;
    int orig = g*HD + unit;
    int swz  = (p & 7) << 3;

    const float* s0 = Whh0 + (size_t)orig*HD;
    const float* s1 = Wih1 + (size_t)orig*HD;
    const float* s2 = Whh1 + (size_t)orig*HD;
    bf16_t* d0 = W0p   + (size_t)p*HD;
    bf16_t* d1 = W1cat + (size_t)p*2048;
    for (int k = threadIdx.x; k < HD; k += blockDim.x) {
        int ks = k ^ swz;
        d0[ks]        = (bf16_t)s0[k];
        d1[ks]        = (bf16_t)s1[k];
        d1[1024 + ks] = (bf16_t)s2[k];
    }
    if (threadIdx.x == 0) {
        bias0p[p] = bih0[orig] + bhh0[orig];
        bias1p[p] = bih1[orig] + bhh1[orig];
        wih0p[p]  = Wih0[orig];
    }
}

__global__ void init_states(const float* __restrict__ h0, const float* __restrict__ c0in,
                            bf16_t* __restrict__ C0, bf16_t* __restrict__ C1,
                            float* __restrict__ cl0, float* __restrict__ cl1)
{
    int i = blockIdx.x * blockDim.x + threadIdx.x;   // 0 .. 1048575
    int row = i >> 10, u = i & 1023;
    int us = u ^ ((row & 7) << 3);
    C1[(size_t)row*2048 + us]        = (bf16_t)h0[i];            // ha_{-1}
    C0[(size_t)row*2048 + 1024 + us] = (bf16_t)h0[1048576 + i];  // hb_{-1}
    cl0[i] = c0in[i];
    cl1[i] = c0in[1048576 + i];
}

// One step-GEMM: gates[BAT][4096] = A(BAT x KTOT, swizzled, stride 2048) @ B^T (4096 x KTOT, swizzled)
// LAYER 0: KTOT=1024, + x*wih0 rank-1 term, cell -> ha into Hout (swizzled), c in cst.
// LAYER 1: KTOT=2048 (A = [ha|hb]),          cell -> hb into Hout (swizzled), + pred atomicAdd.
template<int LAYER>
__global__ __launch_bounds__(512) void step_kernel(
    const bf16_t* __restrict__ A, const bf16_t* __restrict__ B, int Bstride,
    const float* __restrict__ biasp, const float* __restrict__ wih0p,
    bf16_t* __restrict__ Hout, float* __restrict__ cst,
    const float* __restrict__ Wout, const float* __restrict__ bout,
    float* __restrict__ preds, int t)
{
    constexpr int KTOT  = (LAYER == 0) ? 1024 : 2048;
    constexpr int NSTEP = KTOT / BK;
    constexpr int ASTR  = 2048;                 // elements

    __shared__ bf16_t lds[2*16384];             // 2 bufs x (A 8192 + B 8192 elems) = 64 KiB

    int xcd = blockIdx.x & 7;
    int bi  = blockIdx.x >> 3;
    int nt  = xcd*4 + (bi & 3);                 // 0..31  (B-tiles XCD-exclusive)
    int mt  = bi >> 2;                          // 0..7
    int tid = threadIdx.x;
    int lane = tid & 63, w = tid >> 6;
    int rb = w >> 1, cb = w & 1;
    int l15 = lane & 15, lg = lane >> 4;

    int srow = lane >> 3;                       // staging: row within 8-row chunk
    int skb  = (lane & 7) * 16;                 // staging: byte within 128B row
    char* ldsc = (char*)lds;

    f32x4 acc[2][4];
    #pragma unroll
    for (int a_ = 0; a_ < 2; ++a_)
        #pragma unroll
        for (int b_ = 0; b_ < 4; ++b_) acc[a_][b_] = f32x4{0.f,0.f,0.f,0.f};

    auto stage = [&](int buf, int k0) {
        char* base = ldsc + buf*32768;
        #pragma unroll
        for (int q = 0; q < 4; ++q) {
            int c = w*4 + q;                    // 0..31, wave-uniform
            int rl = (c & 15)*8 + srow;
            const char* src;
            if (c < 16) src = (const char*)(A + (size_t)(mt*BM + rl)*ASTR + k0) + skb;
            else        src = (const char*)(B + (size_t)(nt*BN + rl)*(size_t)Bstride + k0) + skb;
            gload_lds16(src, base + c*1024);    // HW scatters lane*16
        }
    };

    stage(0, 0);
    #pragma unroll 1
    for (int s = 0; s < NSTEP; ++s) {
        __syncthreads();                        // drains vmcnt+lgkmcnt
        if (s + 1 < NSTEP) stage((s + 1) & 1, (s + 1)*BK);
        const char* lb = ldsc + (s & 1)*32768;
        #pragma unroll
        for (int ks = 0; ks < 2; ++ks) {
            bf16x8 af[2], bfr[4];
            #pragma unroll
            for (int mi = 0; mi < 2; ++mi) {
                int ar = rb*32 + mi*16 + l15;
                af[mi] = *(const bf16x8*)(lb + ar*128 + ((ks*64 + lg*16) ^ ((ar & 7) << 4)));
            }
            #pragma unroll
            for (int nj = 0; nj < 4; ++nj) {
                int br = cb*64 + nj*16 + l15;
                bfr[nj] = *(const bf16x8*)(lb + 16384 + br*128 + ((ks*64 + lg*16) ^ ((br & 7) << 4)));
            }
            #pragma unroll
            for (int mi = 0; mi < 2; ++mi)
                #pragma unroll
                for (int nj = 0; nj < 4; ++nj)
                    acc[mi][nj] = __builtin_amdgcn_mfma_f32_16x16x32_bf16(af[mi], bfr[nj], acc[mi][nj], 0,0,0);
        }
    }

    // ---------------- epilogue ----------------
    int pbase = nt*128 + cb*64 + l15;
    float bi4[4];
    #pragma unroll
    for (int g = 0; g < 4; ++g) bi4[g] = biasp[pbase + g*16];
    int j = nt*32 + cb*16 + l15;                // hidden unit owned by this lane

    if (LAYER == 0) {
        float wv[4];
        #pragma unroll
        for (int g = 0; g < 4; ++g) wv[g] = wih0p[pbase + g*16];
        #pragma unroll
        for (int mi = 0; mi < 2; ++mi) {
            #pragma unroll
            for (int r = 0; r < 4; ++r) {
                int row = mt*BM + rb*32 + mi*16 + lg*4 + r;
                float x = (t > 0) ? preds[(size_t)row*TT + (t-1)] : 0.f;
                float gi = acc[mi][0][r] + bi4[0] + x*wv[0];
                float gf = acc[mi][1][r] + bi4[1] + x*wv[1];
                float gg = acc[mi][2][r] + bi4[2] + x*wv[2];
                float go = acc[mi][3][r] + bi4[3] + x*wv[3];
                size_t coff = (size_t)row*HD + j;
                float cn = sigm(gf)*cst[coff] + sigm(gi)*tanhfast(gg);
                cst[coff] = cn;
                Hout[(size_t)row*2048 + (j ^ ((row & 7) << 3))] = (bf16_t)(sigm(go)*tanhfast(cn));
            }
        }
    } else {
        float wout = Wout[j];
        #pragma unroll
        for (int mi = 0; mi < 2; ++mi) {
            #pragma unroll
            for (int r = 0; r < 4; ++r) {
                int row = mt*BM + rb*32 + mi*16 + lg*4 + r;
                float gi = acc[mi][0][r] + bi4[0];
                float gf = acc[mi][1][r] + bi4[1];
                float gg = acc[mi][2][r] + bi4[2];
                float go = acc[mi][3][r] + bi4[3];
                size_t coff = (size_t)row*HD + j;
                float cn = sigm(gf)*cst[coff] + sigm(gi)*tanhfast(gg);
                cst[coff] = cn;
                float h = sigm(go)*tanhfast(cn);
                Hout[(size_t)row*2048 + (j ^ ((row & 7) << 3))] = (bf16_t)h;
                float v = h * wout;
                v += __shfl_xor(v, 1, 64);
                v += __shfl_xor(v, 2, 64);
                v += __shfl_xor(v, 4, 64);
                v += __shfl_xor(v, 8, 64);
                if (l15 == 0) {
                    if (nt == 0 && cb == 0) v += bout[0];
                    atomicAdd(&preds[(size_t)row*TT + t], v);
                }
            }
        }
    }
}

__global__ void loss_kernel(const float* __restrict__ preds, const float* __restrict__ targets,
                            float* __restrict__ lossp)
{
    int i = blockIdx.x * blockDim.x + threadIdx.x;   // 0 .. 262143
    float d = preds[i] - targets[i];
    float v = d*d;
    v += __shfl_xor(v, 1, 64);
    v += __shfl_xor(v, 2, 64);
    v += __shfl_xor(v, 4, 64);
    v += __shfl_xor(v, 8, 64);
    v += __shfl_xor(v, 16, 64);
    v += __shfl_xor(v, 32, 64);
    if ((threadIdx.x & 63) == 0) atomicAdd(lossp, v * (1.0f/1024.0f));
}

extern "C" void kernel_launch(void* const* d_in, const int* in_sizes, int n_in,
                              void* d_out, int out_size, void* d_ws, size_t ws_size,
                              hipStream_t stream)
{
    const float* outputs = (const float*)d_in[0];
    const float* h0      = (const float*)d_in[1];
    const float* c0      = (const float*)d_in[2];
    const float* Wih0    = (const float*)d_in[3];
    const float* Whh0    = (const float*)d_in[4];
    const float* bih0    = (const float*)d_in[5];
    const float* bhh0    = (const float*)d_in[6];
    const float* Wih1    = (const float*)d_in[7];
    const float* Whh1    = (const float*)d_in[8];
    const float* bih1    = (const float*)d_in[9];
    const float* bhh1    = (const float*)d_in[10];
    const float* Wout    = (const float*)d_in[11];
    const float* bout    = (const float*)d_in[12];

    uint8_t* ws = (uint8_t*)d_ws;
    size_t o = 0;
    auto alloc = [&](size_t bytes) { void* p = ws + o; o += (bytes + 255) & ~(size_t)255; return p; };
    bf16_t* W0p    = (bf16_t*)alloc((size_t)FH*HD*2);        // 8 MB, permuted+swizzled
    bf16_t* W1cat  = (bf16_t*)alloc((size_t)FH*2048*2);      // 16 MB, [Wih1|Whh1] permuted+swizzled
    bf16_t* Cbuf0  = (bf16_t*)alloc((size_t)BAT*2048*2);     // 4 MB, [ha|hb] swizzled
    bf16_t* Cbuf1  = (bf16_t*)alloc((size_t)BAT*2048*2);
    float*  cl0    = (float*)alloc((size_t)BAT*HD*4);
    float*  cl1    = (float*)alloc((size_t)BAT*HD*4);
    float*  bias0p = (float*)alloc(FH*4);
    float*  bias1p = (float*)alloc(FH*4);
    float*  wih0p  = (float*)alloc(FH*4);
    bf16_t* Cb[2]  = { Cbuf0, Cbuf1 };

    float* preds = (float*)d_out;                            // [BAT][TT] then loss scalar
    hipMemsetAsync(d_out, 0, (size_t)out_size*4, stream);

    prep_weights<<<FH, 256, 0, stream>>>(Whh0, Wih1, Whh1, bih0, bhh0, bih1, bhh1, Wih0,
                                         W0p, W1cat, bias0p, bias1p, wih0p);
    init_states<<<4096, 256, 0, stream>>>(h0, c0, Cbuf0, Cbuf1, cl0, cl1);

    for (int t = 0; t < TT; ++t) {
        bf16_t* Cprev = Cb[(t + 1) & 1];   // holds ha_{t-1} in cols 0:1024
        bf16_t* Ccur  = Cb[t & 1];         // gets ha_t; holds hb_{t-1} in cols 1024:2048
        step_kernel<0><<<256, 512, 0, stream>>>(Cprev, W0p, 1024, bias0p, wih0p,
                                                Ccur, cl0, nullptr, nullptr, preds, t);
        step_kernel<1><<<256, 512, 0, stream>>>(Ccur, W1cat, 2048, bias1p, nullptr,
                                                Cprev + 1024, cl1, Wout, bout, preds, t);
    }
    loss_kernel<<<1024, 256, 0, stream>>>(preds, outputs, preds + (size_t)BAT*TT);
}